// Round 20
// baseline (151.949 us; speedup 1.0000x reference)
//
#include <hip/hip_runtime.h>

// GAT layer. N=100000, E=1.6M, DIN=128, H=4, D=16.
// ROUND 20 = R19 + (A) P1 LDS-histogram fused into k_linear tail (zero global
// atomics; R18-proven tail-fusion shape), (B) k_agg gather pipeline 8 -> 16
// deep (one batch covers avg degree-16 node).

#define DIN 128
#define HD  64
#define NH  4
#define BTP 136
#define BSH 9             // bucket = s >> 9 (512 src values per bucket)

typedef __attribute__((ext_vector_type(8))) short short8;
typedef __attribute__((ext_vector_type(4))) float f32x4;

__device__ __forceinline__ float leaky02(float v) { return v > 0.f ? v : 0.2f * v; }

__device__ __forceinline__ float bf2f(unsigned short u) {
  union { unsigned u32; float f; } c; c.u32 = ((unsigned)u) << 16; return c.f;
}
__device__ __forceinline__ unsigned short f2bf(float f) {
  union { float f; unsigned u; } c; c.f = f;
  unsigned r = c.u + 0x7FFFu + ((c.u >> 16) & 1u);  // RNE
  return (unsigned short)(r >> 16);
}
__device__ __forceinline__ unsigned cvt_pk_bf16(float lo, float hi) {
  unsigned r;
  asm("v_cvt_pk_bf16_f32 %0, %1, %2" : "=v"(r) : "v"(lo), "v"(hi));
  return r;
}

// ---------------- K0: build pre-transposed bf16 fragment table ----------------
__global__ void k_wprep(const float* __restrict__ Wlin, const float* __restrict__ Watt,
                        unsigned short* __restrict__ btg) {
  for (int i = threadIdx.x; i < 80 * BTP; i += 256) {
    const int c = i / BTP, k = i % BTP;
    unsigned short v = 0;
    if (k < DIN) {
      if (c < 64) {
        v = f2bf(Wlin[k * HD + c]);
      } else if (c < 72) {
        const int cc = c - 64;
        const int head = cc & 3, dsth = (cc >= 4) ? 16 : 0;
        float s = 0.f;
#pragma unroll
        for (int d = 0; d < 16; ++d)
          s += Wlin[k * HD + head * 16 + d] * Watt[head * 32 + dsth + d];
        v = f2bf(s);
      }
    }
    btg[i] = v;
  }
}

// ---------------- K1: MFMA linear + fused LDS coarse histogram ----------------
// Block: 512 thr (8 waves), 128 rows. Tail: LDS hist over B coarse buckets
// for this block's edge slice -> bhistT[b*nb + blk]. Zero global atomics.
__global__ __launch_bounds__(512)
void k_linear(const float* __restrict__ x,
              const unsigned short* __restrict__ btg,
              unsigned short* __restrict__ hb,
              float* __restrict__ a_src, float* __restrict__ a_dst,
              int N,
              const int* __restrict__ ei, int* __restrict__ bhistT,
              int E, int B, int nb) {
  __shared__ __align__(16) unsigned short OT[8][16 * 68];
  __shared__ __align__(16) float AT[8][16 * 8];
  __shared__ unsigned lh[256];
  const int tid = threadIdx.x;
  const int lane = tid & 63;
  const int wid  = tid >> 6;

  if (tid < 256) lh[tid] = 0;   // consumed only after the tail barrier

  const int row0 = blockIdx.x * 128 + wid * 16;
  const bool rowok = row0 < N;

  if (rowok) {
    float4 xv[8];
    {
      const int r = min(row0 + (lane & 15), N - 1);
      const float* xp = x + (size_t)r * DIN + ((lane >> 4) * 8);
#pragma unroll
      for (int kt = 0; kt < 4; ++kt) {
        xv[kt * 2 + 0] = *(const float4*)(xp + kt * 32);
        xv[kt * 2 + 1] = *(const float4*)(xp + kt * 32 + 4);
      }
    }

    short8 bf[5][4];
#pragma unroll
    for (int ct = 0; ct < 5; ++ct) {
      const int c = (ct < 4) ? (ct * 16 + (lane & 15)) : (64 + (lane & 15));
#pragma unroll
      for (int kt = 0; kt < 4; ++kt)
        bf[ct][kt] = *(const short8*)(&btg[c * BTP + kt * 32 + (lane >> 4) * 8]);
    }

    short8 af[4];
#pragma unroll
    for (int kt = 0; kt < 4; ++kt) {
      unsigned* ap = (unsigned*)&af[kt];
      const float4 a = xv[kt * 2], b = xv[kt * 2 + 1];
      ap[0] = cvt_pk_bf16(a.x, a.y);
      ap[1] = cvt_pk_bf16(a.z, a.w);
      ap[2] = cvt_pk_bf16(b.x, b.y);
      ap[3] = cvt_pk_bf16(b.z, b.w);
    }
    f32x4 acc[5] = {{0,0,0,0},{0,0,0,0},{0,0,0,0},{0,0,0,0},{0,0,0,0}};
#pragma unroll
    for (int ct = 0; ct < 5; ++ct)
#pragma unroll
      for (int kt = 0; kt < 4; ++kt)
        acc[ct] = __builtin_amdgcn_mfma_f32_16x16x32_bf16(af[kt], bf[ct][kt], acc[ct], 0, 0, 0);

    const int c0 = lane & 15;
    const int r0 = (lane >> 4) * 4;
#pragma unroll
    for (int j = 0; j < 4; ++j) {
#pragma unroll
      for (int ct = 0; ct < 4; ++ct)
        OT[wid][(r0 + j) * 68 + ct * 16 + c0] = f2bf(acc[ct][j]);
      if (c0 < 8) AT[wid][(r0 + j) * 8 + c0] = acc[4][j];
    }
    unsigned* hbu = (unsigned*)(hb + (size_t)row0 * HD);
#pragma unroll
    for (int it = 0; it < 8; ++it) {
      const int rr = it * 2 + (lane >> 5);
      const int cw = lane & 31;
      const unsigned v = *(const unsigned*)&OT[wid][rr * 68 + cw * 2];
      if (row0 + rr < N) hbu[rr * 32 + cw] = v;
    }
    {
      const int rr = lane >> 2, cc = lane & 3;
      if (row0 + rr < N) {
        a_src[(row0 + rr) * 4 + cc] = AT[wid][rr * 8 + cc];
        a_dst[(row0 + rr) * 4 + cc] = AT[wid][rr * 8 + 4 + cc];
      }
    }
  }

  // ---- fused coarse histogram (LDS only) over this block's edge slice ----
  __syncthreads();
  const int per = (E + nb - 1) / nb;
  const int e0 = blockIdx.x * per;
  const int e1 = min(e0 + per, E);
  for (int e = e0 + tid; e < e1; e += 512)
    atomicAdd(&lh[ei[e] >> BSH], 1u);
  __syncthreads();
  if (tid < B) bhistT[tid * nb + blockIdx.x] = (int)lh[tid];
}

// ---------------- K3a/K3b: exclusive scan (proven code) ----------------
__global__ void k_scanA(const int* __restrict__ deg, int* __restrict__ offs,
                        int* __restrict__ partials, int N) {
  __shared__ int wsum[16];
  const int tid = threadIdx.x, lane = tid & 63, wv = tid >> 6;
  int i = blockIdx.x * 1024 + tid;
  int v = (i < N) ? deg[i] : 0;
  int sc = v;
#pragma unroll
  for (int s = 1; s < 64; s <<= 1) {
    int t = __shfl_up(sc, s, 64);
    if (lane >= s) sc += t;
  }
  if (lane == 63) wsum[wv] = sc;
  __syncthreads();
  if (wv == 0 && lane < 16) {
    int w = wsum[lane];
    int s2 = w;
#pragma unroll
    for (int s = 1; s < 16; s <<= 1) {
      int t = __shfl_up(s2, s, 64);
      if (lane >= s) s2 += t;
    }
    wsum[lane] = s2 - w;
  }
  __syncthreads();
  int excl = sc - v + wsum[wv];
  if (i < N) offs[i] = excl;
  if (tid == 1023) partials[blockIdx.x] = excl + v;
}

__global__ void k_scanB(int* __restrict__ offs, const int* __restrict__ partials, int N) {
  __shared__ int sbase;
  const int tid = threadIdx.x, b = blockIdx.x;
  if (tid < 64) {
    int acc = 0;
    for (int j = tid; j < b; j += 64) acc += partials[j];
#pragma unroll
    for (int s = 32; s >= 1; s >>= 1) acc += __shfl_xor(acc, s, 64);
    if (tid == 0) sbase = acc;
  }
  __syncthreads();
  int i = b * 1024 + tid;
  if (i < N) offs[i] += sbase;
}

// ---------------- P3: bucket-partition edges (no global atomics) ----------------
__global__ __launch_bounds__(256)
void k_p3(const int* __restrict__ ei, const int* __restrict__ sbase,
          unsigned long long* __restrict__ tmp, int E, int nb) {
  __shared__ unsigned lh[256];
  const int tid = threadIdx.x, blk = blockIdx.x;
  lh[tid] = 0;
  __syncthreads();
  const int per = (E + nb - 1) / nb;
  const int e0 = blk * per, e1 = min(e0 + per, E);
  for (int e = e0 + tid; e < e1; e += 256) {
    const int s = ei[e];
    const int d = ei[E + e];
    const int b = s >> BSH;
    const unsigned lr = atomicAdd(&lh[b], 1u);   // in-cell rank (any permutation ok)
    const int pos = sbase[b * nb + blk] + (int)lr;
    tmp[pos] = ((unsigned long long)(unsigned)s << 32) | (unsigned)d;
  }
}

// ---------------- P4: per-bucket fine counting sort -> deg, offs, csr ----------------
__global__ __launch_bounds__(256)
void k_p4(const unsigned long long* __restrict__ tmp, const int* __restrict__ sbase,
          int* __restrict__ deg, int* __restrict__ offs, int* __restrict__ csr,
          int E, int N, int B, int nb) {
  __shared__ unsigned lh[512];
  __shared__ unsigned ex[512];
  __shared__ unsigned run[512];
  const int tid = threadIdx.x, b = blockIdx.x;
  const int lo = b << BSH;
  const int start = sbase[b * nb];
  const int end = (b + 1 < B) ? sbase[(b + 1) * nb] : E;

  lh[tid] = 0; lh[tid + 256] = 0;
  __syncthreads();
  for (int i = start + tid; i < end; i += 256)
    atomicAdd(&lh[(unsigned)(tmp[i] >> 32) - lo], 1u);
  __syncthreads();

  if (tid < 64) {
    const int lane = tid;
    unsigned carry = 0;
#pragma unroll
    for (int c = 0; c < 8; ++c) {
      unsigned v = lh[c * 64 + lane];
      unsigned sc = v;
#pragma unroll
      for (int sft = 1; sft < 64; sft <<= 1) {
        unsigned t = __shfl_up(sc, sft, 64);
        if (lane >= sft) sc += t;
      }
      ex[c * 64 + lane] = sc - v + carry;
      carry += __shfl(sc, 63, 64);
    }
  }
  __syncthreads();

  for (int i = tid; i < 512; i += 256) {
    const int n = lo + i;
    if (n < N) {
      deg[n]  = (int)lh[i];
      offs[n] = start + (int)ex[i];
    }
    run[i] = ex[i];
  }
  __syncthreads();

  for (int i = start + tid; i < end; i += 256) {
    const unsigned long long p = tmp[i];
    const unsigned s = (unsigned)(p >> 32);
    const unsigned r = atomicAdd(&run[s - lo], 1u);
    csr[start + (int)r] = (int)(unsigned)p;
  }
}

// ---------------- K5: aggregate, 16-deep gather pipeline ----------------
__global__ __launch_bounds__(256)
void k_agg(const int* __restrict__ offs_start, const int* __restrict__ deg,
           const int* __restrict__ csr, const float4* __restrict__ a_src4,
           const float4* __restrict__ a_dst4,
           const unsigned short* __restrict__ hb,
           float* __restrict__ out, int N) {
  __shared__ float als[4][64 * NH];
  const int lane = threadIdx.x & 63;
  const int wid  = threadIdx.x >> 6;
  const int hh = lane >> 4;
  const int wstride = gridDim.x * 4;

  for (int n0 = blockIdx.x * 4 + wid; n0 < N; n0 += wstride) {
    const int n   = __builtin_amdgcn_readfirstlane(n0);
    const int beg = __builtin_amdgcn_readfirstlane(offs_start[n]);
    const int dg  = __builtin_amdgcn_readfirstlane(deg[n]);
    const int end = beg + dg;
    const float4 asv = a_src4[n];

    float s0 = 0.f, s1 = 0.f, s2 = 0.f, s3 = 0.f;
    float acc0 = 0.f, acc1 = 0.f;
    for (int base = beg; base < end; base += 64) {
      const int cnt = __builtin_amdgcn_readfirstlane(min(64, end - base));
      const bool act = lane < cnt;
      const int d = csr[act ? base + lane : beg];
      const float4 ad = a_dst4[d];
      const float p0 = act ? __expf(leaky02(asv.x + ad.x)) : 0.f;
      const float p1 = act ? __expf(leaky02(asv.y + ad.y)) : 0.f;
      const float p2 = act ? __expf(leaky02(asv.z + ad.z)) : 0.f;
      const float p3 = act ? __expf(leaky02(asv.w + ad.w)) : 0.f;
      s0 += p0; s1 += p1; s2 += p2; s3 += p3;
      *(float4*)&als[wid][lane * 4] = make_float4(p0, p1, p2, p3);

      int j = 0;
      for (; j + 16 <= cnt; j += 16) {  // 16 gathers in flight
        int dds[16];
#pragma unroll
        for (int u = 0; u < 16; ++u)
          dds[u] = __builtin_amdgcn_readfirstlane(csr[base + j + u]);
        float hv[16];
#pragma unroll
        for (int u = 0; u < 16; ++u) hv[u] = bf2f(hb[(size_t)dds[u] * HD + lane]);
#pragma unroll
        for (int u = 0; u < 16; ++u) {
          const float av = als[wid][(j + u) * 4 + hh];
          if (u & 1) acc1 = fmaf(av, hv[u], acc1);
          else       acc0 = fmaf(av, hv[u], acc0);
        }
      }
      for (; j + 8 <= cnt; j += 8) {
        int dds[8];
#pragma unroll
        for (int u = 0; u < 8; ++u)
          dds[u] = __builtin_amdgcn_readfirstlane(csr[base + j + u]);
        float hv[8];
#pragma unroll
        for (int u = 0; u < 8; ++u) hv[u] = bf2f(hb[(size_t)dds[u] * HD + lane]);
#pragma unroll
        for (int u = 0; u < 8; ++u) {
          const float av = als[wid][(j + u) * 4 + hh];
          if (u & 1) acc1 = fmaf(av, hv[u], acc1);
          else       acc0 = fmaf(av, hv[u], acc0);
        }
      }
      for (; j < cnt; ++j) {
        const int dd_ = __builtin_amdgcn_readfirstlane(csr[base + j]);
        const float av = als[wid][j * 4 + hh];
        acc0 = fmaf(av, bf2f(hb[(size_t)dd_ * HD + lane]), acc0);
      }
    }
#pragma unroll
    for (int s = 1; s < 64; s <<= 1) {
      s0 += __shfl_xor(s0, s, 64); s1 += __shfl_xor(s1, s, 64);
      s2 += __shfl_xor(s2, s, 64); s3 += __shfl_xor(s3, s, 64);
    }
    const float sh = (hh == 0) ? s0 : (hh == 1) ? s1 : (hh == 2) ? s2 : s3;
    out[(size_t)n * HD + lane] = (acc0 + acc1) * (1.f / (sh + 1e-16f));
  }
}

extern "C" void kernel_launch(void* const* d_in, const int* in_sizes, int n_in,
                              void* d_out, int out_size, void* d_ws, size_t ws_size,
                              hipStream_t stream) {
  const float* x    = (const float*)d_in[0];
  const int*   ei   = (const int*)d_in[1];
  const float* Wlin = (const float*)d_in[2];
  const float* Watt = (const float*)d_in[3];
  float* out = (float*)d_out;

  const int N = in_sizes[0] / DIN;
  const int E = in_sizes[1] / 2;
  const int B = (N + (1 << BSH) - 1) >> BSH;   // 196 buckets
  const int nb = (N + 127) / 128;              // k_linear grid == edge-slice count
  const int M = B * nb;                        // scan length

  char* ws = (char*)d_ws;
  size_t off = 0;
  auto align16 = [&off]() { off = (off + 15) & ~(size_t)15; };
  unsigned short* hb = (unsigned short*)(ws + off); off += (size_t)N * HD * sizeof(unsigned short); align16();
  float* a_src  = (float*)(ws + off); off += (size_t)N * NH * sizeof(float); align16();
  float* a_dst  = (float*)(ws + off); off += (size_t)N * NH * sizeof(float); align16();
  int*   deg    = (int*)(ws + off);   off += (size_t)N * sizeof(int); align16();
  int*   offs   = (int*)(ws + off);   off += ((size_t)N + 1) * sizeof(int); align16();
  int*   csr    = (int*)(ws + off);   off += (size_t)E * sizeof(int); align16();
  unsigned long long* tmp = (unsigned long long*)(ws + off); off += (size_t)E * sizeof(unsigned long long); align16();
  int*   bhistT = (int*)(ws + off);   off += (size_t)M * sizeof(int); align16();
  int*   sbase  = (int*)(ws + off);   off += (size_t)M * sizeof(int); align16();
  int*   parts  = (int*)(ws + off);   off += 256 * sizeof(int); align16();
  unsigned short* btg = (unsigned short*)(ws + off); off += 80 * BTP * sizeof(unsigned short); align16();

  hipLaunchKernelGGL(k_wprep, dim3(1), dim3(256), 0, stream, Wlin, Watt, btg);

  hipLaunchKernelGGL(k_linear, dim3(nb), dim3(512), 0, stream,
                     x, btg, hb, a_src, a_dst, N, ei, bhistT, E, B, nb);

  const int SB = (M + 1023) / 1024;
  hipLaunchKernelGGL(k_scanA, dim3(SB), dim3(1024), 0, stream, bhistT, sbase, parts, M);
  hipLaunchKernelGGL(k_scanB, dim3(SB), dim3(1024), 0, stream, sbase, parts, M);

  hipLaunchKernelGGL(k_p3, dim3(nb), dim3(256), 0, stream, ei, sbase, tmp, E, nb);

  hipLaunchKernelGGL(k_p4, dim3(B), dim3(256), 0, stream,
                     tmp, sbase, deg, offs, csr, E, N, B, nb);

  hipLaunchKernelGGL(k_agg, dim3(4096), dim3(256), 0, stream,
                     offs, deg, csr, (const float4*)a_src, (const float4*)a_dst, hb, out, N);
}

// Round 21
// 139.481 us; speedup vs baseline: 1.0894x; 1.0894x over previous
//
#include <hip/hip_runtime.h>

// GAT layer. N=100000, E=1.6M, DIN=128, H=4, D=16.
// ROUND 21 = R20 with k_agg REVERTED to R19's 8-deep pipeline (16-deep cost
// 12 VGPR -> occupancy 65->50% -> +12us on the latency-bound gather).
// Keeps R20's fused-P1 k_linear tail (zero global atomics).

#define DIN 128
#define HD  64
#define NH  4
#define BTP 136
#define BSH 9             // bucket = s >> 9 (512 src values per bucket)

typedef __attribute__((ext_vector_type(8))) short short8;
typedef __attribute__((ext_vector_type(4))) float f32x4;

__device__ __forceinline__ float leaky02(float v) { return v > 0.f ? v : 0.2f * v; }

__device__ __forceinline__ float bf2f(unsigned short u) {
  union { unsigned u32; float f; } c; c.u32 = ((unsigned)u) << 16; return c.f;
}
__device__ __forceinline__ unsigned short f2bf(float f) {
  union { float f; unsigned u; } c; c.f = f;
  unsigned r = c.u + 0x7FFFu + ((c.u >> 16) & 1u);  // RNE
  return (unsigned short)(r >> 16);
}
__device__ __forceinline__ unsigned cvt_pk_bf16(float lo, float hi) {
  unsigned r;
  asm("v_cvt_pk_bf16_f32 %0, %1, %2" : "=v"(r) : "v"(lo), "v"(hi));
  return r;
}

// ---------------- K0: build pre-transposed bf16 fragment table ----------------
__global__ void k_wprep(const float* __restrict__ Wlin, const float* __restrict__ Watt,
                        unsigned short* __restrict__ btg) {
  for (int i = threadIdx.x; i < 80 * BTP; i += 256) {
    const int c = i / BTP, k = i % BTP;
    unsigned short v = 0;
    if (k < DIN) {
      if (c < 64) {
        v = f2bf(Wlin[k * HD + c]);
      } else if (c < 72) {
        const int cc = c - 64;
        const int head = cc & 3, dsth = (cc >= 4) ? 16 : 0;
        float s = 0.f;
#pragma unroll
        for (int d = 0; d < 16; ++d)
          s += Wlin[k * HD + head * 16 + d] * Watt[head * 32 + dsth + d];
        v = f2bf(s);
      }
    }
    btg[i] = v;
  }
}

// ---------------- K1: MFMA linear + fused LDS coarse histogram ----------------
__global__ __launch_bounds__(512)
void k_linear(const float* __restrict__ x,
              const unsigned short* __restrict__ btg,
              unsigned short* __restrict__ hb,
              float* __restrict__ a_src, float* __restrict__ a_dst,
              int N,
              const int* __restrict__ ei, int* __restrict__ bhistT,
              int E, int B, int nb) {
  __shared__ __align__(16) unsigned short OT[8][16 * 68];
  __shared__ __align__(16) float AT[8][16 * 8];
  __shared__ unsigned lh[256];
  const int tid = threadIdx.x;
  const int lane = tid & 63;
  const int wid  = tid >> 6;

  if (tid < 256) lh[tid] = 0;   // consumed only after the tail barrier

  const int row0 = blockIdx.x * 128 + wid * 16;
  const bool rowok = row0 < N;

  if (rowok) {
    float4 xv[8];
    {
      const int r = min(row0 + (lane & 15), N - 1);
      const float* xp = x + (size_t)r * DIN + ((lane >> 4) * 8);
#pragma unroll
      for (int kt = 0; kt < 4; ++kt) {
        xv[kt * 2 + 0] = *(const float4*)(xp + kt * 32);
        xv[kt * 2 + 1] = *(const float4*)(xp + kt * 32 + 4);
      }
    }

    short8 bf[5][4];
#pragma unroll
    for (int ct = 0; ct < 5; ++ct) {
      const int c = (ct < 4) ? (ct * 16 + (lane & 15)) : (64 + (lane & 15));
#pragma unroll
      for (int kt = 0; kt < 4; ++kt)
        bf[ct][kt] = *(const short8*)(&btg[c * BTP + kt * 32 + (lane >> 4) * 8]);
    }

    short8 af[4];
#pragma unroll
    for (int kt = 0; kt < 4; ++kt) {
      unsigned* ap = (unsigned*)&af[kt];
      const float4 a = xv[kt * 2], b = xv[kt * 2 + 1];
      ap[0] = cvt_pk_bf16(a.x, a.y);
      ap[1] = cvt_pk_bf16(a.z, a.w);
      ap[2] = cvt_pk_bf16(b.x, b.y);
      ap[3] = cvt_pk_bf16(b.z, b.w);
    }
    f32x4 acc[5] = {{0,0,0,0},{0,0,0,0},{0,0,0,0},{0,0,0,0},{0,0,0,0}};
#pragma unroll
    for (int ct = 0; ct < 5; ++ct)
#pragma unroll
      for (int kt = 0; kt < 4; ++kt)
        acc[ct] = __builtin_amdgcn_mfma_f32_16x16x32_bf16(af[kt], bf[ct][kt], acc[ct], 0, 0, 0);

    const int c0 = lane & 15;
    const int r0 = (lane >> 4) * 4;
#pragma unroll
    for (int j = 0; j < 4; ++j) {
#pragma unroll
      for (int ct = 0; ct < 4; ++ct)
        OT[wid][(r0 + j) * 68 + ct * 16 + c0] = f2bf(acc[ct][j]);
      if (c0 < 8) AT[wid][(r0 + j) * 8 + c0] = acc[4][j];
    }
    unsigned* hbu = (unsigned*)(hb + (size_t)row0 * HD);
#pragma unroll
    for (int it = 0; it < 8; ++it) {
      const int rr = it * 2 + (lane >> 5);
      const int cw = lane & 31;
      const unsigned v = *(const unsigned*)&OT[wid][rr * 68 + cw * 2];
      if (row0 + rr < N) hbu[rr * 32 + cw] = v;
    }
    {
      const int rr = lane >> 2, cc = lane & 3;
      if (row0 + rr < N) {
        a_src[(row0 + rr) * 4 + cc] = AT[wid][rr * 8 + cc];
        a_dst[(row0 + rr) * 4 + cc] = AT[wid][rr * 8 + 4 + cc];
      }
    }
  }

  // ---- fused coarse histogram (LDS only) over this block's edge slice ----
  __syncthreads();
  const int per = (E + nb - 1) / nb;
  const int e0 = blockIdx.x * per;
  const int e1 = min(e0 + per, E);
  for (int e = e0 + tid; e < e1; e += 512)
    atomicAdd(&lh[ei[e] >> BSH], 1u);
  __syncthreads();
  if (tid < B) bhistT[tid * nb + blockIdx.x] = (int)lh[tid];
}

// ---------------- K3a/K3b: exclusive scan (proven code) ----------------
__global__ void k_scanA(const int* __restrict__ deg, int* __restrict__ offs,
                        int* __restrict__ partials, int N) {
  __shared__ int wsum[16];
  const int tid = threadIdx.x, lane = tid & 63, wv = tid >> 6;
  int i = blockIdx.x * 1024 + tid;
  int v = (i < N) ? deg[i] : 0;
  int sc = v;
#pragma unroll
  for (int s = 1; s < 64; s <<= 1) {
    int t = __shfl_up(sc, s, 64);
    if (lane >= s) sc += t;
  }
  if (lane == 63) wsum[wv] = sc;
  __syncthreads();
  if (wv == 0 && lane < 16) {
    int w = wsum[lane];
    int s2 = w;
#pragma unroll
    for (int s = 1; s < 16; s <<= 1) {
      int t = __shfl_up(s2, s, 64);
      if (lane >= s) s2 += t;
    }
    wsum[lane] = s2 - w;
  }
  __syncthreads();
  int excl = sc - v + wsum[wv];
  if (i < N) offs[i] = excl;
  if (tid == 1023) partials[blockIdx.x] = excl + v;
}

__global__ void k_scanB(int* __restrict__ offs, const int* __restrict__ partials, int N) {
  __shared__ int sbase;
  const int tid = threadIdx.x, b = blockIdx.x;
  if (tid < 64) {
    int acc = 0;
    for (int j = tid; j < b; j += 64) acc += partials[j];
#pragma unroll
    for (int s = 32; s >= 1; s >>= 1) acc += __shfl_xor(acc, s, 64);
    if (tid == 0) sbase = acc;
  }
  __syncthreads();
  int i = b * 1024 + tid;
  if (i < N) offs[i] += sbase;
}

// ---------------- P3: bucket-partition edges (no global atomics) ----------------
__global__ __launch_bounds__(256)
void k_p3(const int* __restrict__ ei, const int* __restrict__ sbase,
          unsigned long long* __restrict__ tmp, int E, int nb) {
  __shared__ unsigned lh[256];
  const int tid = threadIdx.x, blk = blockIdx.x;
  lh[tid] = 0;
  __syncthreads();
  const int per = (E + nb - 1) / nb;
  const int e0 = blk * per, e1 = min(e0 + per, E);
  for (int e = e0 + tid; e < e1; e += 256) {
    const int s = ei[e];
    const int d = ei[E + e];
    const int b = s >> BSH;
    const unsigned lr = atomicAdd(&lh[b], 1u);
    const int pos = sbase[b * nb + blk] + (int)lr;
    tmp[pos] = ((unsigned long long)(unsigned)s << 32) | (unsigned)d;
  }
}

// ---------------- P4: per-bucket fine counting sort -> deg, offs, csr ----------------
__global__ __launch_bounds__(256)
void k_p4(const unsigned long long* __restrict__ tmp, const int* __restrict__ sbase,
          int* __restrict__ deg, int* __restrict__ offs, int* __restrict__ csr,
          int E, int N, int B, int nb) {
  __shared__ unsigned lh[512];
  __shared__ unsigned ex[512];
  __shared__ unsigned run[512];
  const int tid = threadIdx.x, b = blockIdx.x;
  const int lo = b << BSH;
  const int start = sbase[b * nb];
  const int end = (b + 1 < B) ? sbase[(b + 1) * nb] : E;

  lh[tid] = 0; lh[tid + 256] = 0;
  __syncthreads();
  for (int i = start + tid; i < end; i += 256)
    atomicAdd(&lh[(unsigned)(tmp[i] >> 32) - lo], 1u);
  __syncthreads();

  if (tid < 64) {
    const int lane = tid;
    unsigned carry = 0;
#pragma unroll
    for (int c = 0; c < 8; ++c) {
      unsigned v = lh[c * 64 + lane];
      unsigned sc = v;
#pragma unroll
      for (int sft = 1; sft < 64; sft <<= 1) {
        unsigned t = __shfl_up(sc, sft, 64);
        if (lane >= sft) sc += t;
      }
      ex[c * 64 + lane] = sc - v + carry;
      carry += __shfl(sc, 63, 64);
    }
  }
  __syncthreads();

  for (int i = tid; i < 512; i += 256) {
    const int n = lo + i;
    if (n < N) {
      deg[n]  = (int)lh[i];
      offs[n] = start + (int)ex[i];
    }
    run[i] = ex[i];
  }
  __syncthreads();

  for (int i = start + tid; i < end; i += 256) {
    const unsigned long long p = tmp[i];
    const unsigned s = (unsigned)(p >> 32);
    const unsigned r = atomicAdd(&run[s - lo], 1u);
    csr[start + (int)r] = (int)(unsigned)p;
  }
}

// ---------------- K5: aggregate, 8-deep pipeline (R19 verbatim) ----------------
__global__ __launch_bounds__(256)
void k_agg(const int* __restrict__ offs_start, const int* __restrict__ deg,
           const int* __restrict__ csr, const float4* __restrict__ a_src4,
           const float4* __restrict__ a_dst4,
           const unsigned short* __restrict__ hb,
           float* __restrict__ out, int N) {
  __shared__ float als[4][64 * NH];
  const int lane = threadIdx.x & 63;
  const int wid  = threadIdx.x >> 6;
  const int hh = lane >> 4;
  const int wstride = gridDim.x * 4;

  for (int n0 = blockIdx.x * 4 + wid; n0 < N; n0 += wstride) {
    const int n   = __builtin_amdgcn_readfirstlane(n0);
    const int beg = __builtin_amdgcn_readfirstlane(offs_start[n]);
    const int dg  = __builtin_amdgcn_readfirstlane(deg[n]);
    const int end = beg + dg;
    const float4 asv = a_src4[n];

    float s0 = 0.f, s1 = 0.f, s2 = 0.f, s3 = 0.f;
    float acc0 = 0.f, acc1 = 0.f;
    for (int base = beg; base < end; base += 64) {
      const int cnt = __builtin_amdgcn_readfirstlane(min(64, end - base));
      const bool act = lane < cnt;
      const int d = csr[act ? base + lane : beg];
      const float4 ad = a_dst4[d];
      const float p0 = act ? __expf(leaky02(asv.x + ad.x)) : 0.f;
      const float p1 = act ? __expf(leaky02(asv.y + ad.y)) : 0.f;
      const float p2 = act ? __expf(leaky02(asv.z + ad.z)) : 0.f;
      const float p3 = act ? __expf(leaky02(asv.w + ad.w)) : 0.f;
      s0 += p0; s1 += p1; s2 += p2; s3 += p3;
      *(float4*)&als[wid][lane * 4] = make_float4(p0, p1, p2, p3);

      int j = 0;
      for (; j + 8 <= cnt; j += 8) {
        int dds[8];
#pragma unroll
        for (int u = 0; u < 8; ++u)
          dds[u] = __builtin_amdgcn_readfirstlane(csr[base + j + u]);
        float hv[8];
#pragma unroll
        for (int u = 0; u < 8; ++u) hv[u] = bf2f(hb[(size_t)dds[u] * HD + lane]);
#pragma unroll
        for (int u = 0; u < 8; ++u) {
          const float av = als[wid][(j + u) * 4 + hh];
          if (u & 1) acc1 = fmaf(av, hv[u], acc1);
          else       acc0 = fmaf(av, hv[u], acc0);
        }
      }
      for (; j < cnt; ++j) {
        const int dd_ = __builtin_amdgcn_readfirstlane(csr[base + j]);
        const float av = als[wid][j * 4 + hh];
        acc0 = fmaf(av, bf2f(hb[(size_t)dd_ * HD + lane]), acc0);
      }
    }
#pragma unroll
    for (int s = 1; s < 64; s <<= 1) {
      s0 += __shfl_xor(s0, s, 64); s1 += __shfl_xor(s1, s, 64);
      s2 += __shfl_xor(s2, s, 64); s3 += __shfl_xor(s3, s, 64);
    }
    const float sh = (hh == 0) ? s0 : (hh == 1) ? s1 : (hh == 2) ? s2 : s3;
    out[(size_t)n * HD + lane] = (acc0 + acc1) * (1.f / (sh + 1e-16f));
  }
}

extern "C" void kernel_launch(void* const* d_in, const int* in_sizes, int n_in,
                              void* d_out, int out_size, void* d_ws, size_t ws_size,
                              hipStream_t stream) {
  const float* x    = (const float*)d_in[0];
  const int*   ei   = (const int*)d_in[1];
  const float* Wlin = (const float*)d_in[2];
  const float* Watt = (const float*)d_in[3];
  float* out = (float*)d_out;

  const int N = in_sizes[0] / DIN;
  const int E = in_sizes[1] / 2;
  const int B = (N + (1 << BSH) - 1) >> BSH;   // 196 buckets
  const int nb = (N + 127) / 128;              // k_linear grid == edge-slice count
  const int M = B * nb;                        // scan length

  char* ws = (char*)d_ws;
  size_t off = 0;
  auto align16 = [&off]() { off = (off + 15) & ~(size_t)15; };
  unsigned short* hb = (unsigned short*)(ws + off); off += (size_t)N * HD * sizeof(unsigned short); align16();
  float* a_src  = (float*)(ws + off); off += (size_t)N * NH * sizeof(float); align16();
  float* a_dst  = (float*)(ws + off); off += (size_t)N * NH * sizeof(float); align16();
  int*   deg    = (int*)(ws + off);   off += (size_t)N * sizeof(int); align16();
  int*   offs   = (int*)(ws + off);   off += ((size_t)N + 1) * sizeof(int); align16();
  int*   csr    = (int*)(ws + off);   off += (size_t)E * sizeof(int); align16();
  unsigned long long* tmp = (unsigned long long*)(ws + off); off += (size_t)E * sizeof(unsigned long long); align16();
  int*   bhistT = (int*)(ws + off);   off += (size_t)M * sizeof(int); align16();
  int*   sbase  = (int*)(ws + off);   off += (size_t)M * sizeof(int); align16();
  int*   parts  = (int*)(ws + off);   off += 256 * sizeof(int); align16();
  unsigned short* btg = (unsigned short*)(ws + off); off += 80 * BTP * sizeof(unsigned short); align16();

  hipLaunchKernelGGL(k_wprep, dim3(1), dim3(256), 0, stream, Wlin, Watt, btg);

  hipLaunchKernelGGL(k_linear, dim3(nb), dim3(512), 0, stream,
                     x, btg, hb, a_src, a_dst, N, ei, bhistT, E, B, nb);

  const int SB = (M + 1023) / 1024;
  hipLaunchKernelGGL(k_scanA, dim3(SB), dim3(1024), 0, stream, bhistT, sbase, parts, M);
  hipLaunchKernelGGL(k_scanB, dim3(SB), dim3(1024), 0, stream, sbase, parts, M);

  hipLaunchKernelGGL(k_p3, dim3(nb), dim3(256), 0, stream, ei, sbase, tmp, E, nb);

  hipLaunchKernelGGL(k_p4, dim3(B), dim3(256), 0, stream,
                     tmp, sbase, deg, offs, csr, E, N, B, nb);

  hipLaunchKernelGGL(k_agg, dim3(4096), dim3(256), 0, stream,
                     offs, deg, csr, (const float4*)a_src, (const float4*)a_dst, hb, out, N);
}

// Round 22
// 131.499 us; speedup vs baseline: 1.1555x; 1.0607x over previous
//
#include <hip/hip_runtime.h>

// GAT layer. N=100000, E=1.6M, DIN=128, H=4, D=16.
// ROUND 22 = R21 + (A) k_wprep parallelized (43 blocks), (B) tmp packed to
// 32-bit (slo<<17 | d): halves P3 write + P4 read traffic. k_linear geometry
// and k_agg untouched (R21 verbatim).

#define DIN 128
#define HD  64
#define NH  4
#define BTP 136
#define BSH 9             // bucket = s >> 9 (512 src values per bucket)

typedef __attribute__((ext_vector_type(8))) short short8;
typedef __attribute__((ext_vector_type(4))) float f32x4;

__device__ __forceinline__ float leaky02(float v) { return v > 0.f ? v : 0.2f * v; }

__device__ __forceinline__ float bf2f(unsigned short u) {
  union { unsigned u32; float f; } c; c.u32 = ((unsigned)u) << 16; return c.f;
}
__device__ __forceinline__ unsigned short f2bf(float f) {
  union { float f; unsigned u; } c; c.f = f;
  unsigned r = c.u + 0x7FFFu + ((c.u >> 16) & 1u);  // RNE
  return (unsigned short)(r >> 16);
}
__device__ __forceinline__ unsigned cvt_pk_bf16(float lo, float hi) {
  unsigned r;
  asm("v_cvt_pk_bf16_f32 %0, %1, %2" : "=v"(r) : "v"(lo), "v"(hi));
  return r;
}

// ---------------- K0: build pre-transposed bf16 fragment table (parallel) ----------------
__global__ void k_wprep(const float* __restrict__ Wlin, const float* __restrict__ Watt,
                        unsigned short* __restrict__ btg) {
  const int i = blockIdx.x * 256 + threadIdx.x;
  if (i >= 80 * BTP) return;
  const int c = i / BTP, k = i % BTP;
  unsigned short v = 0;
  if (k < DIN) {
    if (c < 64) {
      v = f2bf(Wlin[k * HD + c]);
    } else if (c < 72) {
      const int cc = c - 64;
      const int head = cc & 3, dsth = (cc >= 4) ? 16 : 0;
      float s = 0.f;
#pragma unroll
      for (int d = 0; d < 16; ++d)
        s += Wlin[k * HD + head * 16 + d] * Watt[head * 32 + dsth + d];
      v = f2bf(s);
    }
  }
  btg[i] = v;
}

// ---------------- K1: MFMA linear + fused LDS coarse histogram (R21 verbatim) ----------------
__global__ __launch_bounds__(512)
void k_linear(const float* __restrict__ x,
              const unsigned short* __restrict__ btg,
              unsigned short* __restrict__ hb,
              float* __restrict__ a_src, float* __restrict__ a_dst,
              int N,
              const int* __restrict__ ei, int* __restrict__ bhistT,
              int E, int B, int nb) {
  __shared__ __align__(16) unsigned short OT[8][16 * 68];
  __shared__ __align__(16) float AT[8][16 * 8];
  __shared__ unsigned lh[256];
  const int tid = threadIdx.x;
  const int lane = tid & 63;
  const int wid  = tid >> 6;

  if (tid < 256) lh[tid] = 0;   // consumed only after the tail barrier

  const int row0 = blockIdx.x * 128 + wid * 16;
  const bool rowok = row0 < N;

  if (rowok) {
    float4 xv[8];
    {
      const int r = min(row0 + (lane & 15), N - 1);
      const float* xp = x + (size_t)r * DIN + ((lane >> 4) * 8);
#pragma unroll
      for (int kt = 0; kt < 4; ++kt) {
        xv[kt * 2 + 0] = *(const float4*)(xp + kt * 32);
        xv[kt * 2 + 1] = *(const float4*)(xp + kt * 32 + 4);
      }
    }

    short8 bf[5][4];
#pragma unroll
    for (int ct = 0; ct < 5; ++ct) {
      const int c = (ct < 4) ? (ct * 16 + (lane & 15)) : (64 + (lane & 15));
#pragma unroll
      for (int kt = 0; kt < 4; ++kt)
        bf[ct][kt] = *(const short8*)(&btg[c * BTP + kt * 32 + (lane >> 4) * 8]);
    }

    short8 af[4];
#pragma unroll
    for (int kt = 0; kt < 4; ++kt) {
      unsigned* ap = (unsigned*)&af[kt];
      const float4 a = xv[kt * 2], b = xv[kt * 2 + 1];
      ap[0] = cvt_pk_bf16(a.x, a.y);
      ap[1] = cvt_pk_bf16(a.z, a.w);
      ap[2] = cvt_pk_bf16(b.x, b.y);
      ap[3] = cvt_pk_bf16(b.z, b.w);
    }
    f32x4 acc[5] = {{0,0,0,0},{0,0,0,0},{0,0,0,0},{0,0,0,0},{0,0,0,0}};
#pragma unroll
    for (int ct = 0; ct < 5; ++ct)
#pragma unroll
      for (int kt = 0; kt < 4; ++kt)
        acc[ct] = __builtin_amdgcn_mfma_f32_16x16x32_bf16(af[kt], bf[ct][kt], acc[ct], 0, 0, 0);

    const int c0 = lane & 15;
    const int r0 = (lane >> 4) * 4;
#pragma unroll
    for (int j = 0; j < 4; ++j) {
#pragma unroll
      for (int ct = 0; ct < 4; ++ct)
        OT[wid][(r0 + j) * 68 + ct * 16 + c0] = f2bf(acc[ct][j]);
      if (c0 < 8) AT[wid][(r0 + j) * 8 + c0] = acc[4][j];
    }
    unsigned* hbu = (unsigned*)(hb + (size_t)row0 * HD);
#pragma unroll
    for (int it = 0; it < 8; ++it) {
      const int rr = it * 2 + (lane >> 5);
      const int cw = lane & 31;
      const unsigned v = *(const unsigned*)&OT[wid][rr * 68 + cw * 2];
      if (row0 + rr < N) hbu[rr * 32 + cw] = v;
    }
    {
      const int rr = lane >> 2, cc = lane & 3;
      if (row0 + rr < N) {
        a_src[(row0 + rr) * 4 + cc] = AT[wid][rr * 8 + cc];
        a_dst[(row0 + rr) * 4 + cc] = AT[wid][rr * 8 + 4 + cc];
      }
    }
  }

  // ---- fused coarse histogram (LDS only) over this block's edge slice ----
  __syncthreads();
  const int per = (E + nb - 1) / nb;
  const int e0 = blockIdx.x * per;
  const int e1 = min(e0 + per, E);
  for (int e = e0 + tid; e < e1; e += 512)
    atomicAdd(&lh[ei[e] >> BSH], 1u);
  __syncthreads();
  if (tid < B) bhistT[tid * nb + blockIdx.x] = (int)lh[tid];
}

// ---------------- K3a/K3b: exclusive scan (proven code) ----------------
__global__ void k_scanA(const int* __restrict__ deg, int* __restrict__ offs,
                        int* __restrict__ partials, int N) {
  __shared__ int wsum[16];
  const int tid = threadIdx.x, lane = tid & 63, wv = tid >> 6;
  int i = blockIdx.x * 1024 + tid;
  int v = (i < N) ? deg[i] : 0;
  int sc = v;
#pragma unroll
  for (int s = 1; s < 64; s <<= 1) {
    int t = __shfl_up(sc, s, 64);
    if (lane >= s) sc += t;
  }
  if (lane == 63) wsum[wv] = sc;
  __syncthreads();
  if (wv == 0 && lane < 16) {
    int w = wsum[lane];
    int s2 = w;
#pragma unroll
    for (int s = 1; s < 16; s <<= 1) {
      int t = __shfl_up(s2, s, 64);
      if (lane >= s) s2 += t;
    }
    wsum[lane] = s2 - w;
  }
  __syncthreads();
  int excl = sc - v + wsum[wv];
  if (i < N) offs[i] = excl;
  if (tid == 1023) partials[blockIdx.x] = excl + v;
}

__global__ void k_scanB(int* __restrict__ offs, const int* __restrict__ partials, int N) {
  __shared__ int sbase;
  const int tid = threadIdx.x, b = blockIdx.x;
  if (tid < 64) {
    int acc = 0;
    for (int j = tid; j < b; j += 64) acc += partials[j];
#pragma unroll
    for (int s = 32; s >= 1; s >>= 1) acc += __shfl_xor(acc, s, 64);
    if (tid == 0) sbase = acc;
  }
  __syncthreads();
  int i = b * 1024 + tid;
  if (i < N) offs[i] += sbase;
}

// ---------------- P3: bucket-partition edges, 32-bit packed (slo<<17 | d) ----------------
__global__ __launch_bounds__(256)
void k_p3(const int* __restrict__ ei, const int* __restrict__ sbase,
          unsigned* __restrict__ tmp, int E, int nb) {
  __shared__ unsigned lh[256];
  const int tid = threadIdx.x, blk = blockIdx.x;
  lh[tid] = 0;
  __syncthreads();
  const int per = (E + nb - 1) / nb;
  const int e0 = blk * per, e1 = min(e0 + per, E);
  for (int e = e0 + tid; e < e1; e += 256) {
    const int s = ei[e];
    const int d = ei[E + e];
    const int b = s >> BSH;
    const unsigned lr = atomicAdd(&lh[b], 1u);
    const int pos = sbase[b * nb + blk] + (int)lr;
    tmp[pos] = ((unsigned)(s & ((1 << BSH) - 1)) << 17) | (unsigned)d;
  }
}

// ---------------- P4: per-bucket fine counting sort -> deg, offs, csr ----------------
__global__ __launch_bounds__(256)
void k_p4(const unsigned* __restrict__ tmp, const int* __restrict__ sbase,
          int* __restrict__ deg, int* __restrict__ offs, int* __restrict__ csr,
          int E, int N, int B, int nb) {
  __shared__ unsigned lh[512];
  __shared__ unsigned ex[512];
  __shared__ unsigned run[512];
  const int tid = threadIdx.x, b = blockIdx.x;
  const int lo = b << BSH;
  const int start = sbase[b * nb];
  const int end = (b + 1 < B) ? sbase[(b + 1) * nb] : E;

  lh[tid] = 0; lh[tid + 256] = 0;
  __syncthreads();
  for (int i = start + tid; i < end; i += 256)
    atomicAdd(&lh[tmp[i] >> 17], 1u);
  __syncthreads();

  if (tid < 64) {
    const int lane = tid;
    unsigned carry = 0;
#pragma unroll
    for (int c = 0; c < 8; ++c) {
      unsigned v = lh[c * 64 + lane];
      unsigned sc = v;
#pragma unroll
      for (int sft = 1; sft < 64; sft <<= 1) {
        unsigned t = __shfl_up(sc, sft, 64);
        if (lane >= sft) sc += t;
      }
      ex[c * 64 + lane] = sc - v + carry;
      carry += __shfl(sc, 63, 64);
    }
  }
  __syncthreads();

  for (int i = tid; i < 512; i += 256) {
    const int n = lo + i;
    if (n < N) {
      deg[n]  = (int)lh[i];
      offs[n] = start + (int)ex[i];
    }
    run[i] = ex[i];
  }
  __syncthreads();

  for (int i = start + tid; i < end; i += 256) {
    const unsigned p = tmp[i];
    const unsigned slo = p >> 17;
    const unsigned r = atomicAdd(&run[slo], 1u);
    csr[start + (int)r] = (int)(p & 0x1FFFFu);
  }
}

// ---------------- K5: aggregate, 8-deep pipeline (R21 verbatim) ----------------
__global__ __launch_bounds__(256)
void k_agg(const int* __restrict__ offs_start, const int* __restrict__ deg,
           const int* __restrict__ csr, const float4* __restrict__ a_src4,
           const float4* __restrict__ a_dst4,
           const unsigned short* __restrict__ hb,
           float* __restrict__ out, int N) {
  __shared__ float als[4][64 * NH];
  const int lane = threadIdx.x & 63;
  const int wid  = threadIdx.x >> 6;
  const int hh = lane >> 4;
  const int wstride = gridDim.x * 4;

  for (int n0 = blockIdx.x * 4 + wid; n0 < N; n0 += wstride) {
    const int n   = __builtin_amdgcn_readfirstlane(n0);
    const int beg = __builtin_amdgcn_readfirstlane(offs_start[n]);
    const int dg  = __builtin_amdgcn_readfirstlane(deg[n]);
    const int end = beg + dg;
    const float4 asv = a_src4[n];

    float s0 = 0.f, s1 = 0.f, s2 = 0.f, s3 = 0.f;
    float acc0 = 0.f, acc1 = 0.f;
    for (int base = beg; base < end; base += 64) {
      const int cnt = __builtin_amdgcn_readfirstlane(min(64, end - base));
      const bool act = lane < cnt;
      const int d = csr[act ? base + lane : beg];
      const float4 ad = a_dst4[d];
      const float p0 = act ? __expf(leaky02(asv.x + ad.x)) : 0.f;
      const float p1 = act ? __expf(leaky02(asv.y + ad.y)) : 0.f;
      const float p2 = act ? __expf(leaky02(asv.z + ad.z)) : 0.f;
      const float p3 = act ? __expf(leaky02(asv.w + ad.w)) : 0.f;
      s0 += p0; s1 += p1; s2 += p2; s3 += p3;
      *(float4*)&als[wid][lane * 4] = make_float4(p0, p1, p2, p3);

      int j = 0;
      for (; j + 8 <= cnt; j += 8) {
        int dds[8];
#pragma unroll
        for (int u = 0; u < 8; ++u)
          dds[u] = __builtin_amdgcn_readfirstlane(csr[base + j + u]);
        float hv[8];
#pragma unroll
        for (int u = 0; u < 8; ++u) hv[u] = bf2f(hb[(size_t)dds[u] * HD + lane]);
#pragma unroll
        for (int u = 0; u < 8; ++u) {
          const float av = als[wid][(j + u) * 4 + hh];
          if (u & 1) acc1 = fmaf(av, hv[u], acc1);
          else       acc0 = fmaf(av, hv[u], acc0);
        }
      }
      for (; j < cnt; ++j) {
        const int dd_ = __builtin_amdgcn_readfirstlane(csr[base + j]);
        const float av = als[wid][j * 4 + hh];
        acc0 = fmaf(av, bf2f(hb[(size_t)dd_ * HD + lane]), acc0);
      }
    }
#pragma unroll
    for (int s = 1; s < 64; s <<= 1) {
      s0 += __shfl_xor(s0, s, 64); s1 += __shfl_xor(s1, s, 64);
      s2 += __shfl_xor(s2, s, 64); s3 += __shfl_xor(s3, s, 64);
    }
    const float sh = (hh == 0) ? s0 : (hh == 1) ? s1 : (hh == 2) ? s2 : s3;
    out[(size_t)n * HD + lane] = (acc0 + acc1) * (1.f / (sh + 1e-16f));
  }
}

extern "C" void kernel_launch(void* const* d_in, const int* in_sizes, int n_in,
                              void* d_out, int out_size, void* d_ws, size_t ws_size,
                              hipStream_t stream) {
  const float* x    = (const float*)d_in[0];
  const int*   ei   = (const int*)d_in[1];
  const float* Wlin = (const float*)d_in[2];
  const float* Watt = (const float*)d_in[3];
  float* out = (float*)d_out;

  const int N = in_sizes[0] / DIN;
  const int E = in_sizes[1] / 2;
  const int B = (N + (1 << BSH) - 1) >> BSH;   // 196 buckets
  const int nb = (N + 127) / 128;              // k_linear grid == edge-slice count
  const int M = B * nb;                        // scan length

  char* ws = (char*)d_ws;
  size_t off = 0;
  auto align16 = [&off]() { off = (off + 15) & ~(size_t)15; };
  unsigned short* hb = (unsigned short*)(ws + off); off += (size_t)N * HD * sizeof(unsigned short); align16();
  float* a_src  = (float*)(ws + off); off += (size_t)N * NH * sizeof(float); align16();
  float* a_dst  = (float*)(ws + off); off += (size_t)N * NH * sizeof(float); align16();
  int*   deg    = (int*)(ws + off);   off += (size_t)N * sizeof(int); align16();
  int*   offs   = (int*)(ws + off);   off += ((size_t)N + 1) * sizeof(int); align16();
  int*   csr    = (int*)(ws + off);   off += (size_t)E * sizeof(int); align16();
  unsigned* tmp = (unsigned*)(ws + off); off += (size_t)E * sizeof(unsigned); align16();
  int*   bhistT = (int*)(ws + off);   off += (size_t)M * sizeof(int); align16();
  int*   sbase  = (int*)(ws + off);   off += (size_t)M * sizeof(int); align16();
  int*   parts  = (int*)(ws + off);   off += 256 * sizeof(int); align16();
  unsigned short* btg = (unsigned short*)(ws + off); off += 80 * BTP * sizeof(unsigned short); align16();

  hipLaunchKernelGGL(k_wprep, dim3((80 * BTP + 255) / 256), dim3(256), 0, stream,
                     Wlin, Watt, btg);

  hipLaunchKernelGGL(k_linear, dim3(nb), dim3(512), 0, stream,
                     x, btg, hb, a_src, a_dst, N, ei, bhistT, E, B, nb);

  const int SB = (M + 1023) / 1024;
  hipLaunchKernelGGL(k_scanA, dim3(SB), dim3(1024), 0, stream, bhistT, sbase, parts, M);
  hipLaunchKernelGGL(k_scanB, dim3(SB), dim3(1024), 0, stream, sbase, parts, M);

  hipLaunchKernelGGL(k_p3, dim3(nb), dim3(256), 0, stream, ei, sbase, tmp, E, nb);

  hipLaunchKernelGGL(k_p4, dim3(B), dim3(256), 0, stream,
                     tmp, sbase, deg, offs, csr, E, N, B, nb);

  hipLaunchKernelGGL(k_agg, dim3(4096), dim3(256), 0, stream,
                     offs, deg, csr, (const float4*)a_src, (const float4*)a_dst, hb, out, N);
}

// Round 23
// 127.728 us; speedup vs baseline: 1.1896x; 1.0295x over previous
//
#include <hip/hip_runtime.h>

// GAT layer. N=100000, E=1.6M, DIN=128, H=4, D=16.
// ROUND 23 = R22 + scanB MERGED into P3/P4: scanA's partials (150 vals) are
// prefix-summed in-kernel by one wave; P3 materializes its 196 per-bucket
// bases once in LDS (replacing per-edge global sbase gathers); P4 computes
// its 2 boundary bases likewise. scanB kernel deleted. k_linear/k_agg verbatim.

#define DIN 128
#define HD  64
#define NH  4
#define BTP 136
#define BSH 9             // bucket = s >> 9 (512 src values per bucket)

typedef __attribute__((ext_vector_type(8))) short short8;
typedef __attribute__((ext_vector_type(4))) float f32x4;

__device__ __forceinline__ float leaky02(float v) { return v > 0.f ? v : 0.2f * v; }

__device__ __forceinline__ float bf2f(unsigned short u) {
  union { unsigned u32; float f; } c; c.u32 = ((unsigned)u) << 16; return c.f;
}
__device__ __forceinline__ unsigned short f2bf(float f) {
  union { float f; unsigned u; } c; c.f = f;
  unsigned r = c.u + 0x7FFFu + ((c.u >> 16) & 1u);  // RNE
  return (unsigned short)(r >> 16);
}
__device__ __forceinline__ unsigned cvt_pk_bf16(float lo, float hi) {
  unsigned r;
  asm("v_cvt_pk_bf16_f32 %0, %1, %2" : "=v"(r) : "v"(lo), "v"(hi));
  return r;
}

// ---------------- K0: build pre-transposed bf16 fragment table (parallel) ----------------
__global__ void k_wprep(const float* __restrict__ Wlin, const float* __restrict__ Watt,
                        unsigned short* __restrict__ btg) {
  const int i = blockIdx.x * 256 + threadIdx.x;
  if (i >= 80 * BTP) return;
  const int c = i / BTP, k = i % BTP;
  unsigned short v = 0;
  if (k < DIN) {
    if (c < 64) {
      v = f2bf(Wlin[k * HD + c]);
    } else if (c < 72) {
      const int cc = c - 64;
      const int head = cc & 3, dsth = (cc >= 4) ? 16 : 0;
      float s = 0.f;
#pragma unroll
      for (int d = 0; d < 16; ++d)
        s += Wlin[k * HD + head * 16 + d] * Watt[head * 32 + dsth + d];
      v = f2bf(s);
    }
  }
  btg[i] = v;
}

// ---------------- K1: MFMA linear + fused LDS coarse histogram (verbatim) ----------------
__global__ __launch_bounds__(512)
void k_linear(const float* __restrict__ x,
              const unsigned short* __restrict__ btg,
              unsigned short* __restrict__ hb,
              float* __restrict__ a_src, float* __restrict__ a_dst,
              int N,
              const int* __restrict__ ei, int* __restrict__ bhistT,
              int E, int B, int nb) {
  __shared__ __align__(16) unsigned short OT[8][16 * 68];
  __shared__ __align__(16) float AT[8][16 * 8];
  __shared__ unsigned lh[256];
  const int tid = threadIdx.x;
  const int lane = tid & 63;
  const int wid  = tid >> 6;

  if (tid < 256) lh[tid] = 0;

  const int row0 = blockIdx.x * 128 + wid * 16;
  const bool rowok = row0 < N;

  if (rowok) {
    float4 xv[8];
    {
      const int r = min(row0 + (lane & 15), N - 1);
      const float* xp = x + (size_t)r * DIN + ((lane >> 4) * 8);
#pragma unroll
      for (int kt = 0; kt < 4; ++kt) {
        xv[kt * 2 + 0] = *(const float4*)(xp + kt * 32);
        xv[kt * 2 + 1] = *(const float4*)(xp + kt * 32 + 4);
      }
    }

    short8 bf[5][4];
#pragma unroll
    for (int ct = 0; ct < 5; ++ct) {
      const int c = (ct < 4) ? (ct * 16 + (lane & 15)) : (64 + (lane & 15));
#pragma unroll
      for (int kt = 0; kt < 4; ++kt)
        bf[ct][kt] = *(const short8*)(&btg[c * BTP + kt * 32 + (lane >> 4) * 8]);
    }

    short8 af[4];
#pragma unroll
    for (int kt = 0; kt < 4; ++kt) {
      unsigned* ap = (unsigned*)&af[kt];
      const float4 a = xv[kt * 2], b = xv[kt * 2 + 1];
      ap[0] = cvt_pk_bf16(a.x, a.y);
      ap[1] = cvt_pk_bf16(a.z, a.w);
      ap[2] = cvt_pk_bf16(b.x, b.y);
      ap[3] = cvt_pk_bf16(b.z, b.w);
    }
    f32x4 acc[5] = {{0,0,0,0},{0,0,0,0},{0,0,0,0},{0,0,0,0},{0,0,0,0}};
#pragma unroll
    for (int ct = 0; ct < 5; ++ct)
#pragma unroll
      for (int kt = 0; kt < 4; ++kt)
        acc[ct] = __builtin_amdgcn_mfma_f32_16x16x32_bf16(af[kt], bf[ct][kt], acc[ct], 0, 0, 0);

    const int c0 = lane & 15;
    const int r0 = (lane >> 4) * 4;
#pragma unroll
    for (int j = 0; j < 4; ++j) {
#pragma unroll
      for (int ct = 0; ct < 4; ++ct)
        OT[wid][(r0 + j) * 68 + ct * 16 + c0] = f2bf(acc[ct][j]);
      if (c0 < 8) AT[wid][(r0 + j) * 8 + c0] = acc[4][j];
    }
    unsigned* hbu = (unsigned*)(hb + (size_t)row0 * HD);
#pragma unroll
    for (int it = 0; it < 8; ++it) {
      const int rr = it * 2 + (lane >> 5);
      const int cw = lane & 31;
      const unsigned v = *(const unsigned*)&OT[wid][rr * 68 + cw * 2];
      if (row0 + rr < N) hbu[rr * 32 + cw] = v;
    }
    {
      const int rr = lane >> 2, cc = lane & 3;
      if (row0 + rr < N) {
        a_src[(row0 + rr) * 4 + cc] = AT[wid][rr * 8 + cc];
        a_dst[(row0 + rr) * 4 + cc] = AT[wid][rr * 8 + 4 + cc];
      }
    }
  }

  __syncthreads();
  const int per = (E + nb - 1) / nb;
  const int e0 = blockIdx.x * per;
  const int e1 = min(e0 + per, E);
  for (int e = e0 + tid; e < e1; e += 512)
    atomicAdd(&lh[ei[e] >> BSH], 1u);
  __syncthreads();
  if (tid < B) bhistT[tid * nb + blockIdx.x] = (int)lh[tid];
}

// ---------------- K3a: per-block exclusive scan (partials NOT folded in) ----------------
__global__ void k_scanA(const int* __restrict__ deg, int* __restrict__ offs,
                        int* __restrict__ partials, int N) {
  __shared__ int wsum[16];
  const int tid = threadIdx.x, lane = tid & 63, wv = tid >> 6;
  int i = blockIdx.x * 1024 + tid;
  int v = (i < N) ? deg[i] : 0;
  int sc = v;
#pragma unroll
  for (int s = 1; s < 64; s <<= 1) {
    int t = __shfl_up(sc, s, 64);
    if (lane >= s) sc += t;
  }
  if (lane == 63) wsum[wv] = sc;
  __syncthreads();
  if (wv == 0 && lane < 16) {
    int w = wsum[lane];
    int s2 = w;
#pragma unroll
    for (int s = 1; s < 16; s <<= 1) {
      int t = __shfl_up(s2, s, 64);
      if (lane >= s) s2 += t;
    }
    wsum[lane] = s2 - w;
  }
  __syncthreads();
  int excl = sc - v + wsum[wv];
  if (i < N) offs[i] = excl;
  if (tid == 1023) partials[blockIdx.x] = excl + v;
}

// ---------------- P3: bucket-partition, in-kernel partials prefix + LDS bases ----------------
__global__ __launch_bounds__(256)
void k_p3(const int* __restrict__ ei, const int* __restrict__ sbaseA,
          const int* __restrict__ partials, int SB,
          unsigned* __restrict__ tmp, int E, int B, int nb) {
  __shared__ unsigned lh[256];
  __shared__ int pfx[256];     // exclusive prefix of partials[0..SB), SB <= 256
  __shared__ int base_s[256];  // per-bucket global base for this slice
  const int tid = threadIdx.x, blk = blockIdx.x;
  lh[tid] = 0;
  __syncthreads();

  // one wave: exclusive prefix of partials
  if (tid < 64) {
    const int lane = tid;
    int carry = 0;
    for (int c = 0; c * 64 < SB; ++c) {
      const int idx = c * 64 + lane;
      int v = (idx < SB) ? partials[idx] : 0;
      int sc = v;
#pragma unroll
      for (int sft = 1; sft < 64; sft <<= 1) {
        int t = __shfl_up(sc, sft, 64);
        if (lane >= sft) sc += t;
      }
      if (idx < 256) pfx[idx] = sc - v + carry;
      carry += __shfl(sc, 63, 64);
    }
  }
  __syncthreads();

  // per-bucket bases for this slice
  if (tid < B) {
    const int cell = tid * nb + blk;
    base_s[tid] = sbaseA[cell] + pfx[cell >> 10];
  }
  __syncthreads();

  const int per = (E + nb - 1) / nb;
  const int e0 = blk * per, e1 = min(e0 + per, E);
  for (int e = e0 + tid; e < e1; e += 256) {
    const int s = ei[e];
    const int d = ei[E + e];
    const int b = s >> BSH;
    const unsigned lr = atomicAdd(&lh[b], 1u);
    const int pos = base_s[b] + (int)lr;
    tmp[pos] = ((unsigned)(s & ((1 << BSH) - 1)) << 17) | (unsigned)d;
  }
}

// ---------------- P4: per-bucket fine counting sort (computes own bases) ----------------
__global__ __launch_bounds__(256)
void k_p4(const unsigned* __restrict__ tmp, const int* __restrict__ sbaseA,
          const int* __restrict__ partials, int SB,
          int* __restrict__ deg, int* __restrict__ offs, int* __restrict__ csr,
          int E, int N, int B, int nb) {
  __shared__ unsigned lh[512];
  __shared__ unsigned ex[512];
  __shared__ unsigned run[512];
  __shared__ int bounds[2];
  const int tid = threadIdx.x, b = blockIdx.x;
  const int lo = b << BSH;

  // two threads compute the boundary bases (prefix over <=SB partials each)
  if (tid < 2) {
    int res;
    if (tid == 1 && b + 1 >= B) {
      res = E;
    } else {
      const int cell = (b + tid) * nb;
      int p = 0;
      const int sb = cell >> 10;
      for (int j = 0; j < sb; ++j) p += partials[j];
      res = sbaseA[cell] + p;
    }
    bounds[tid] = res;
  }
  lh[tid] = 0; lh[tid + 256] = 0;
  __syncthreads();
  const int start = bounds[0];
  const int end   = bounds[1];

  for (int i = start + tid; i < end; i += 256)
    atomicAdd(&lh[tmp[i] >> 17], 1u);
  __syncthreads();

  if (tid < 64) {
    const int lane = tid;
    unsigned carry = 0;
#pragma unroll
    for (int c = 0; c < 8; ++c) {
      unsigned v = lh[c * 64 + lane];
      unsigned sc = v;
#pragma unroll
      for (int sft = 1; sft < 64; sft <<= 1) {
        unsigned t = __shfl_up(sc, sft, 64);
        if (lane >= sft) sc += t;
      }
      ex[c * 64 + lane] = sc - v + carry;
      carry += __shfl(sc, 63, 64);
    }
  }
  __syncthreads();

  for (int i = tid; i < 512; i += 256) {
    const int n = lo + i;
    if (n < N) {
      deg[n]  = (int)lh[i];
      offs[n] = start + (int)ex[i];
    }
    run[i] = ex[i];
  }
  __syncthreads();

  for (int i = start + tid; i < end; i += 256) {
    const unsigned p = tmp[i];
    const unsigned slo = p >> 17;
    const unsigned r = atomicAdd(&run[slo], 1u);
    csr[start + (int)r] = (int)(p & 0x1FFFFu);
  }
}

// ---------------- K5: aggregate, 8-deep pipeline (verbatim) ----------------
__global__ __launch_bounds__(256)
void k_agg(const int* __restrict__ offs_start, const int* __restrict__ deg,
           const int* __restrict__ csr, const float4* __restrict__ a_src4,
           const float4* __restrict__ a_dst4,
           const unsigned short* __restrict__ hb,
           float* __restrict__ out, int N) {
  __shared__ float als[4][64 * NH];
  const int lane = threadIdx.x & 63;
  const int wid  = threadIdx.x >> 6;
  const int hh = lane >> 4;
  const int wstride = gridDim.x * 4;

  for (int n0 = blockIdx.x * 4 + wid; n0 < N; n0 += wstride) {
    const int n   = __builtin_amdgcn_readfirstlane(n0);
    const int beg = __builtin_amdgcn_readfirstlane(offs_start[n]);
    const int dg  = __builtin_amdgcn_readfirstlane(deg[n]);
    const int end = beg + dg;
    const float4 asv = a_src4[n];

    float s0 = 0.f, s1 = 0.f, s2 = 0.f, s3 = 0.f;
    float acc0 = 0.f, acc1 = 0.f;
    for (int base = beg; base < end; base += 64) {
      const int cnt = __builtin_amdgcn_readfirstlane(min(64, end - base));
      const bool act = lane < cnt;
      const int d = csr[act ? base + lane : beg];
      const float4 ad = a_dst4[d];
      const float p0 = act ? __expf(leaky02(asv.x + ad.x)) : 0.f;
      const float p1 = act ? __expf(leaky02(asv.y + ad.y)) : 0.f;
      const float p2 = act ? __expf(leaky02(asv.z + ad.z)) : 0.f;
      const float p3 = act ? __expf(leaky02(asv.w + ad.w)) : 0.f;
      s0 += p0; s1 += p1; s2 += p2; s3 += p3;
      *(float4*)&als[wid][lane * 4] = make_float4(p0, p1, p2, p3);

      int j = 0;
      for (; j + 8 <= cnt; j += 8) {
        int dds[8];
#pragma unroll
        for (int u = 0; u < 8; ++u)
          dds[u] = __builtin_amdgcn_readfirstlane(csr[base + j + u]);
        float hv[8];
#pragma unroll
        for (int u = 0; u < 8; ++u) hv[u] = bf2f(hb[(size_t)dds[u] * HD + lane]);
#pragma unroll
        for (int u = 0; u < 8; ++u) {
          const float av = als[wid][(j + u) * 4 + hh];
          if (u & 1) acc1 = fmaf(av, hv[u], acc1);
          else       acc0 = fmaf(av, hv[u], acc0);
        }
      }
      for (; j < cnt; ++j) {
        const int dd_ = __builtin_amdgcn_readfirstlane(csr[base + j]);
        const float av = als[wid][j * 4 + hh];
        acc0 = fmaf(av, bf2f(hb[(size_t)dd_ * HD + lane]), acc0);
      }
    }
#pragma unroll
    for (int s = 1; s < 64; s <<= 1) {
      s0 += __shfl_xor(s0, s, 64); s1 += __shfl_xor(s1, s, 64);
      s2 += __shfl_xor(s2, s, 64); s3 += __shfl_xor(s3, s, 64);
    }
    const float sh = (hh == 0) ? s0 : (hh == 1) ? s1 : (hh == 2) ? s2 : s3;
    out[(size_t)n * HD + lane] = (acc0 + acc1) * (1.f / (sh + 1e-16f));
  }
}

extern "C" void kernel_launch(void* const* d_in, const int* in_sizes, int n_in,
                              void* d_out, int out_size, void* d_ws, size_t ws_size,
                              hipStream_t stream) {
  const float* x    = (const float*)d_in[0];
  const int*   ei   = (const int*)d_in[1];
  const float* Wlin = (const float*)d_in[2];
  const float* Watt = (const float*)d_in[3];
  float* out = (float*)d_out;

  const int N = in_sizes[0] / DIN;
  const int E = in_sizes[1] / 2;
  const int B = (N + (1 << BSH) - 1) >> BSH;   // 196 buckets
  const int nb = (N + 127) / 128;              // k_linear grid == edge-slice count
  const int M = B * nb;                        // scan length
  const int SB = (M + 1023) / 1024;            // scan blocks (= partials count)

  char* ws = (char*)d_ws;
  size_t off = 0;
  auto align16 = [&off]() { off = (off + 15) & ~(size_t)15; };
  unsigned short* hb = (unsigned short*)(ws + off); off += (size_t)N * HD * sizeof(unsigned short); align16();
  float* a_src  = (float*)(ws + off); off += (size_t)N * NH * sizeof(float); align16();
  float* a_dst  = (float*)(ws + off); off += (size_t)N * NH * sizeof(float); align16();
  int*   deg    = (int*)(ws + off);   off += (size_t)N * sizeof(int); align16();
  int*   offs   = (int*)(ws + off);   off += ((size_t)N + 1) * sizeof(int); align16();
  int*   csr    = (int*)(ws + off);   off += (size_t)E * sizeof(int); align16();
  unsigned* tmp = (unsigned*)(ws + off); off += (size_t)E * sizeof(unsigned); align16();
  int*   bhistT = (int*)(ws + off);   off += (size_t)M * sizeof(int); align16();
  int*   sbase  = (int*)(ws + off);   off += (size_t)M * sizeof(int); align16();
  int*   parts  = (int*)(ws + off);   off += 256 * sizeof(int); align16();
  unsigned short* btg = (unsigned short*)(ws + off); off += 80 * BTP * sizeof(unsigned short); align16();

  hipLaunchKernelGGL(k_wprep, dim3((80 * BTP + 255) / 256), dim3(256), 0, stream,
                     Wlin, Watt, btg);

  hipLaunchKernelGGL(k_linear, dim3(nb), dim3(512), 0, stream,
                     x, btg, hb, a_src, a_dst, N, ei, bhistT, E, B, nb);

  hipLaunchKernelGGL(k_scanA, dim3(SB), dim3(1024), 0, stream, bhistT, sbase, parts, M);

  hipLaunchKernelGGL(k_p3, dim3(nb), dim3(256), 0, stream,
                     ei, sbase, parts, SB, tmp, E, B, nb);

  hipLaunchKernelGGL(k_p4, dim3(B), dim3(256), 0, stream,
                     tmp, sbase, parts, SB, deg, offs, csr, E, N, B, nb);

  hipLaunchKernelGGL(k_agg, dim3(4096), dim3(256), 0, stream,
                     offs, deg, csr, (const float4*)a_src, (const float4*)a_dst, hb, out, N);
}